// Round 10
// baseline (215.836 us; speedup 1.0000x reference)
//
#include <hip/hip_runtime.h>

typedef __bf16 bf16x8 __attribute__((ext_vector_type(8)));
typedef float  f32x4  __attribute__((ext_vector_type(4)));
typedef unsigned short ushortx8 __attribute__((ext_vector_type(8)));
typedef unsigned short ushortx4 __attribute__((ext_vector_type(4)));

static __device__ __forceinline__ unsigned short f2bf(float f) {
  unsigned int u = __builtin_bit_cast(unsigned int, f);
  u += 0x7FFFu + ((u >> 16) & 1u);
  return (unsigned short)(u >> 16);
}
static __device__ __forceinline__ unsigned short f2bf_fast(float f) {  // round-half-up
  unsigned int u = __builtin_bit_cast(unsigned int, f);
  return (unsigned short)((u + 0x8000u) >> 16);
}

#define GLL16(gp, lp) __builtin_amdgcn_global_load_lds(                       \
    (const __attribute__((address_space(1))) void*)(gp),                      \
    (__attribute__((address_space(3))) void*)(lp), 16, 0, 0)

// ---------------- prep: z<4 -> transpose+cast W; z>=4 -> cast X fp32->bf16 ----------------
__global__ __launch_bounds__(256) void prep_kernel(const float* __restrict__ X,
                                                   const float* __restrict__ W0,
                                                   const float* __restrict__ W1,
                                                   const float* __restrict__ W2,
                                                   const float* __restrict__ W3,
                                                   unsigned short* __restrict__ Xbf,
                                                   unsigned short* __restrict__ D0,
                                                   unsigned short* __restrict__ D1,
                                                   unsigned short* __restrict__ D2,
                                                   unsigned short* __restrict__ D3) {
  int z = blockIdx.z;
  if (z >= 4) {  // cast 4096x1024 fp32 -> bf16; z in {4,5}
    long bid = (long)(z - 4) * 1024 + blockIdx.y * 32 + blockIdx.x;
    int tl = threadIdx.y * 32 + threadIdx.x;
    long i = bid * 2048 + (long)tl * 8;
    float4 f0 = *(const float4*)(X + i);
    float4 f1 = *(const float4*)(X + i + 4);
    ushortx8 u;
    u[0] = f2bf(f0.x); u[1] = f2bf(f0.y); u[2] = f2bf(f0.z); u[3] = f2bf(f0.w);
    u[4] = f2bf(f1.x); u[5] = f2bf(f1.y); u[6] = f2bf(f1.z); u[7] = f2bf(f1.w);
    *(ushortx8*)(Xbf + i) = u;
    return;
  }
  const float* src = (z == 0) ? W0 : (z == 1) ? W1 : (z == 2) ? W2 : W3;
  unsigned short* dst = (z == 0) ? D0 : (z == 1) ? D1 : (z == 2) ? D2 : D3;
  const int R = 1024, C = 1024;
  __shared__ unsigned short t[32][33];
  int c = blockIdx.x * 32 + threadIdx.x;
#pragma unroll
  for (int i = 0; i < 4; ++i) {
    int r = blockIdx.y * 32 + threadIdx.y + i * 8;
    t[threadIdx.y + i * 8][threadIdx.x] = f2bf(src[(size_t)r * C + c]);
  }
  __syncthreads();
  int rr = blockIdx.y * 32 + threadIdx.x;
#pragma unroll
  for (int i = 0; i < 4; ++i) {
    int cc = blockIdx.x * 32 + threadIdx.y + i * 8;
    dst[(size_t)cc * R + rr] = t[threadIdx.x][threadIdx.y + i * 8];
  }
}

// ---------------- QKV GEMM: 128x128 tile, BK=32, 3-deep LDS ring, counted vmcnt ----
// 48KB LDS -> 3 blocks/CU residency (TLP hides the counted wait). 4 loads/thread/tile,
// prefetch distance 2. Trailing vmcnt(4). z: 0=Q (RoPE, pre-scaled), 1=K (RoPE), 2=V^T.
__global__ __launch_bounds__(256, 3) void qkvr_kernel(
    const unsigned short* __restrict__ A,
    const unsigned short* __restrict__ BT0,
    const unsigned short* __restrict__ BT1,
    const unsigned short* __restrict__ BT2,
    unsigned short* __restrict__ outQ,
    unsigned short* __restrict__ outK,
    unsigned short* __restrict__ outVT,
    const int* __restrict__ pos_ids,
    const float* __restrict__ cosb,
    const float* __restrict__ sinb) {
  const int K = 1024;
  int id = blockIdx.x + 8 * (blockIdx.y + 32 * blockIdx.z);
  int m_idx = id & 31;         // m fastest => xcd = id%8 = m_idx%8
  int nzi = id >> 5;
  int n_idx = nzi & 7;
  int z = nzi >> 3;
  const unsigned short* BT = (z == 0) ? BT0 : (z == 1 ? BT1 : BT2);
  int n0 = n_idx * 128, m0 = m_idx * 128;
  int t = threadIdx.x, lane = t & 63, w = t >> 6;
  int wy = w >> 1, wx = w & 1;
  int n16 = lane & 15, quad = lane >> 4;

  __shared__ __align__(16) unsigned short sA[3][128][32];
  __shared__ __align__(16) unsigned short sB[3][128][32];
  __shared__ __align__(16) unsigned short sDummy[512];  // tail sink (never read)
  const int BUFE = 128 * 32;

  int r4 = lane >> 2, c4 = lane & 3;
  const char* gA = (const char*)(A + (size_t)(m0 + w * 32 + r4) * K) + ((c4 ^ (r4 & 3)) * 16);
  const char* gB = (const char*)(BT + (size_t)(n0 + w * 32 + r4) * K) + ((c4 ^ (r4 & 3)) * 16);
  const size_t row16 = (size_t)16 * K * 2;
  unsigned short* stA = &sA[0][w * 32][0];
  unsigned short* stB = &sB[0][w * 32][0];

  int cs = (quad ^ (n16 & 3)) * 8;
  const unsigned short* rdA = &sA[0][wy * 64 + n16][0] + cs;
  const unsigned short* rdB = &sB[0][wx * 64 + n16][0] + cs;

  f32x4 acc[4][4];
#pragma unroll
  for (int i = 0; i < 4; ++i)
#pragma unroll
    for (int j = 0; j < 4; ++j) acc[i][j] = f32x4{0.f, 0.f, 0.f, 0.f};

  bf16x8 a[4], b[4];

#define QSTG(tt, dA, dB)                                                        \
  do {                                                                          \
    GLL16(gA + (size_t)(tt) * 64, (dA));                                        \
    GLL16(gA + (size_t)(tt) * 64 + row16, (dA) + 16 * 32);                      \
    GLL16(gB + (size_t)(tt) * 64, (dB));                                        \
    GLL16(gB + (size_t)(tt) * 64 + row16, (dB) + 16 * 32);                      \
  } while (0)

#define QRD(bufi)                                                               \
  do {                                                                          \
    _Pragma("unroll") for (int i = 0; i < 4; ++i) {                             \
      a[i] = *(const bf16x8*)(rdA + (bufi) * BUFE + (i * 16) * 32);             \
      b[i] = *(const bf16x8*)(rdB + (bufi) * BUFE + (i * 16) * 32);             \
    }                                                                           \
  } while (0)

#define QMM                                                                     \
  do {                                                                          \
    _Pragma("unroll") for (int mt = 0; mt < 4; ++mt)                            \
      _Pragma("unroll") for (int nt = 0; nt < 4; ++nt)                          \
        acc[mt][nt] = __builtin_amdgcn_mfma_f32_16x16x32_bf16(                  \
            a[mt], b[nt], acc[mt][nt], 0, 0, 0);                                \
  } while (0)

  // prologue: stage tiles 0,1 (8 loads); vmcnt(4) -> tile0 landed, tile1 in flight
  QSTG(0, stA, stB);
  QSTG(1, stA + BUFE, stB + BUFE);
  asm volatile("s_waitcnt vmcnt(4)" ::: "memory");
  __builtin_amdgcn_s_barrier();

#pragma unroll 3
  for (int kt = 0; kt < 30; ++kt) {
    int buf = kt % 3;
    int pfb = (kt + 2) % 3;
    QRD(buf);
    QSTG(kt + 2, stA + pfb * BUFE, stB + pfb * BUFE);
    QMM;
    asm volatile("s_waitcnt vmcnt(4)" ::: "memory");
    __builtin_amdgcn_s_barrier();
  }
  // tail: tiles 30 (buf 0) and 31 (buf 1); dummy staging keeps vmcnt uniform
  {
    QRD(0);
    QSTG(31, sDummy, sDummy);  // addresses valid (tile31 global), dest is sink
    QMM;
    asm volatile("s_waitcnt vmcnt(4)" ::: "memory");
    __builtin_amdgcn_s_barrier();
  }
  {
    QRD(1);
    QSTG(31, sDummy, sDummy);
    QMM;
    asm volatile("s_waitcnt vmcnt(0)" ::: "memory");  // drain sinks before epilogue
  }
#undef QSTG
#undef QRD
#undef QMM

  if (z < 2) {  // fused RoPE on Q/K; Q additionally pre-scaled by SCALE*log2(e)
    const float qs = (z == 0) ? (0.125f * 1.44269504088896340736f) : 1.0f;
#pragma unroll
    for (int mt = 0; mt < 4; ++mt)
#pragma unroll
      for (int r = 0; r < 4; ++r) {
        int row = m0 + wy * 64 + mt * 16 + quad * 4 + r;
        int b_ = row >> 11, s_ = row & 2047;
        int pos = pos_ids[b_ * 2048 + s_];
        const float* cb = cosb + (size_t)pos * 64;
        const float* sb = sinb + (size_t)pos * 64;
#pragma unroll
        for (int nt = 0; nt < 2; ++nt) {
          int d0 = nt * 16 + n16;
          float c0 = cb[d0] * qs, s0 = sb[d0] * qs;
          float c1 = cb[d0 + 32] * qs, s1 = sb[d0 + 32] * qs;
          float x0 = acc[mt][nt][r], x1 = acc[mt][nt + 2][r];
          acc[mt][nt][r]     = x0 * c0 - x1 * s0;
          acc[mt][nt + 2][r] = x1 * c1 + x0 * s1;
        }
      }
    unsigned short* dst = (z == 0) ? outQ : outK;
#pragma unroll
    for (int mt = 0; mt < 4; ++mt)
#pragma unroll
      for (int nt = 0; nt < 4; ++nt)
#pragma unroll
        for (int r = 0; r < 4; ++r) {
          int row = m0 + wy * 64 + mt * 16 + quad * 4 + r;
          int col = n0 + wx * 64 + nt * 16 + n16;
          int b_ = row >> 11, s_ = row & 2047, h_ = col >> 6, d_ = col & 63;
          dst[(((size_t)b_ * 16 + h_) * 2048 + s_) * 64 + d_] = f2bf(acc[mt][nt][r]);
        }
    return;
  }

  // z == 2: V^T fused write: VT[((b*16+h)*64+d)*2048 + s]; 4 consecutive s per lane
#pragma unroll
  for (int mt = 0; mt < 4; ++mt)
#pragma unroll
    for (int nt = 0; nt < 4; ++nt) {
      int row = m0 + wy * 64 + mt * 16 + quad * 4;  // +r stays within one b
      int b_ = row >> 11, s_ = row & 2047;
      int col = n0 + wx * 64 + nt * 16 + n16;
      int h_ = col >> 6, d_ = col & 63;
      ushortx4 u;
#pragma unroll
      for (int r = 0; r < 4; ++r) u[r] = f2bf(acc[mt][nt][r]);
      *(ushortx4*)(&outVT[(((size_t)b_ * 16 + h_) * 64 + d_) * 2048 + s_]) = u;
    }
}

// ---------------- Wo GEMM: 128x64 tile, BK=32, 3-deep ring, counted vmcnt ----
// M=4096 x N=1024 -> 512 blocks (2/CU). id = bx + 8*by, m fastest -> xcd = m%8
// (A-panels L2-pinned per XCD). 3 loads/thread/tile (2A+1B) -> trailing vmcnt(3).
__global__ __launch_bounds__(256) void wor_kernel(const unsigned short* __restrict__ A,
                                                  const unsigned short* __restrict__ BT,
                                                  float* __restrict__ outF) {
  const int K = 1024, N = 1024;
  int id = blockIdx.x + 8 * blockIdx.y;  // grid (8,64)
  int m_idx = id & 31, n_idx = id >> 5;
  int m0 = m_idx * 128, n0 = n_idx * 64;
  int t = threadIdx.x, lane = t & 63, w = t >> 6;
  int wy = w >> 1, wx = w & 1;
  int n16 = lane & 15, quad = lane >> 4;

  __shared__ __align__(16) unsigned short sA[3][128][32];
  __shared__ __align__(16) unsigned short sB[3][64][32];
  __shared__ __align__(16) unsigned short sDummy[512];
  const int BUFA = 128 * 32, BUFB = 64 * 32;

  int r4 = lane >> 2, c4 = lane & 3;
  const char* gA = (const char*)(A + (size_t)(m0 + w * 32 + r4) * K) + ((c4 ^ (r4 & 3)) * 16);
  const char* gB = (const char*)(BT + (size_t)(n0 + w * 16 + r4) * K) + ((c4 ^ (r4 & 3)) * 16);
  const size_t row16 = (size_t)16 * K * 2;
  unsigned short* stA = &sA[0][w * 32][0];
  unsigned short* stB = &sB[0][w * 16][0];

  int cs = (quad ^ (n16 & 3)) * 8;
  const unsigned short* rdA = &sA[0][wy * 64 + n16][0] + cs;
  const unsigned short* rdB = &sB[0][wx * 32 + n16][0] + cs;

  f32x4 acc[4][2];
#pragma unroll
  for (int i = 0; i < 4; ++i)
#pragma unroll
    for (int j = 0; j < 2; ++j) acc[i][j] = f32x4{0.f, 0.f, 0.f, 0.f};

  bf16x8 a[4], b[2];

#define WSTG(tt, dA, dB)                                                        \
  do {                                                                          \
    GLL16(gA + (size_t)(tt) * 64, (dA));                                        \
    GLL16(gA + (size_t)(tt) * 64 + row16, (dA) + 16 * 32);                      \
    GLL16(gB + (size_t)(tt) * 64, (dB));                                        \
  } while (0)

#define WRD(bufi)                                                               \
  do {                                                                          \
    _Pragma("unroll") for (int i = 0; i < 4; ++i)                               \
      a[i] = *(const bf16x8*)(rdA + (bufi) * BUFA + (i * 16) * 32);             \
    _Pragma("unroll") for (int j = 0; j < 2; ++j)                               \
      b[j] = *(const bf16x8*)(rdB + (bufi) * BUFB + (j * 16) * 32);             \
  } while (0)

#define WMM                                                                     \
  do {                                                                          \
    _Pragma("unroll") for (int mt = 0; mt < 4; ++mt)                            \
      _Pragma("unroll") for (int nt = 0; nt < 2; ++nt)                          \
        acc[mt][nt] = __builtin_amdgcn_mfma_f32_16x16x32_bf16(                  \
            a[mt], b[nt], acc[mt][nt], 0, 0, 0);                                \
  } while (0)

  WSTG(0, stA, stB);
  WSTG(1, stA + BUFA, stB + BUFB);
  asm volatile("s_waitcnt vmcnt(3)" ::: "memory");
  __builtin_amdgcn_s_barrier();

#pragma unroll 3
  for (int kt = 0; kt < 30; ++kt) {
    int buf = kt % 3;
    int pfb = (kt + 2) % 3;
    WRD(buf);
    WSTG(kt + 2, stA + pfb * BUFA, stB + pfb * BUFB);
    WMM;
    asm volatile("s_waitcnt vmcnt(3)" ::: "memory");
    __builtin_amdgcn_s_barrier();
  }
  {
    WRD(0);
    WSTG(31, sDummy, sDummy);
    WMM;
    asm volatile("s_waitcnt vmcnt(3)" ::: "memory");
    __builtin_amdgcn_s_barrier();
  }
  {
    WRD(1);
    WSTG(31, sDummy, sDummy);
    WMM;
    asm volatile("s_waitcnt vmcnt(0)" ::: "memory");
  }
#undef WSTG
#undef WRD
#undef WMM

#pragma unroll
  for (int mt = 0; mt < 4; ++mt)
#pragma unroll
    for (int nt = 0; nt < 2; ++nt)
#pragma unroll
      for (int r = 0; r < 4; ++r) {
        int row = m0 + wy * 64 + mt * 16 + quad * 4 + r;
        int col = n0 + wx * 32 + nt * 16 + n16;
        outF[(size_t)row * N + col] = acc[mt][nt][r];
      }
}

// ---------------- Flash attention: 4 waves, q-tile 128 (2 sub-blocks/wave) ----
// Per-wave pipeline from the proven R5/R7 kernel; each wave now owns TWO 16-row
// q-sub-blocks (qg0 at w*16, qg1 at +64) sharing the SAME K/V LDS fragments: 16
// shared ds_reads feed 32 MFMAs, K/V staging+fetch per unit work halves, and the
// two independent softmax chains give intra-wave ILP over the P-LDS roundtrip.
// nk = 2*qt+2 staged 64-k tiles; sub0 masks from tile nk-2 (diag) and is naturally
// all-masked (p->0) on tile nk-1. grid (32,16): xcd = bh%8 (K/V L2-pinned per head).
__global__ __launch_bounds__(256) void attn_kernel(const unsigned short* __restrict__ Q,
                                                   const unsigned short* __restrict__ Kk,
                                                   const unsigned short* __restrict__ VT,
                                                   unsigned short* __restrict__ O) {
  int bh = blockIdx.x;
  int qt = 15 - (int)blockIdx.y;  // LPT: largest q-tile first
  int t = threadIdx.x;
  int lane = t & 63;
  int w = t >> 6;          // 0..3
  int n16 = lane & 15, quad = lane >> 4;
  int r8 = lane >> 3, c8 = lane & 7;
  const unsigned short* Qb = Q + (size_t)bh * 2048 * 64;
  const unsigned short* Kb = Kk + (size_t)bh * 2048 * 64;
  const unsigned short* Vb = VT + (size_t)bh * 64 * 2048;

  __shared__ __align__(16) unsigned short sKV[2 * 8192];  // [buf][K 4096 | V 4096]
  __shared__ __align__(16) unsigned short sP[4][2][16 * 64];
  unsigned short* spW0 = sP[w][0];
  unsigned short* spW1 = sP[w][1];

  int b_ = bh >> 4, h_ = bh & 15;
  int nk = 2 * qt + 2;
  int qg0 = qt * 128 + w * 16 + n16;
  int qg1 = qg0 + 64;

  bf16x8 aQ0[2], aQ1[2];
#pragma unroll
  for (int kb = 0; kb < 2; ++kb) {
    aQ0[kb] = *(const bf16x8*)(Qb + (size_t)qg0 * 64 + kb * 32 + quad * 8);
    aQ1[kb] = *(const bf16x8*)(Qb + (size_t)qg1 * 64 + kb * 32 + quad * 8);
  }

  f32x4 o0[4], o1[4];
  float mst0 = -3e38f, lst0 = 0.f, mst1 = -3e38f, lst1 = 0.f;
#pragma unroll
  for (int ct = 0; ct < 4; ++ct) {
    o0[ct] = f32x4{0.f, 0.f, 0.f, 0.f};
    o1[ct] = f32x4{0.f, 0.f, 0.f, 0.f};
  }

#define ASTAGE(kt_, BUF)                                                                  \
  do {                                                                                    \
    const unsigned short* kg_ = Kb + (size_t)((kt_) * 64 + w * 16) * 64;                  \
    const unsigned short* vg_ = Vb + (size_t)(w * 16) * 2048 + (kt_) * 64;                \
    unsigned short* dK = sKV + (BUF) * 8192 + (w * 16) * 64;                              \
    unsigned short* dV = dK + 4096;                                                       \
    GLL16(kg_ + (size_t)r8 * 64 + (c8 ^ r8) * 8, dK);                                     \
    GLL16(kg_ + (size_t)(8 + r8) * 64 + (c8 ^ r8) * 8, dK + 8 * 64);                      \
    GLL16(vg_ + (size_t)r8 * 2048 + (c8 ^ r8) * 8, dV);                                   \
    GLL16(vg_ + (size_t)(8 + r8) * 2048 + (c8 ^ r8) * 8, dV + 8 * 64);                    \
  } while (0)

// one softmax chain: consumes SC into P-store at SPW; updates MST/LST, rescales OO.
// MASKC = compile-side condition for applying the causal mask with row limit QG.
#define SOFTMAX_SUB(SC, QG, MASKC, MST, LST, OO, SPW)                                     \
  do {                                                                                    \
    float p[4][4];                                                                        \
    _Pragma("unroll") for (int mt = 0; mt < 4; ++mt)                                      \
      _Pragma("unroll") for (int r = 0; r < 4; ++r) p[mt][r] = SC[mt][r];                 \
    if (MASKC) {                                                                          \
      int kb0 = (kt_) * 64 + quad * 4;                                                    \
      _Pragma("unroll") for (int mt = 0; mt < 4; ++mt)                                    \
        _Pragma("unroll") for (int r = 0; r < 4; ++r)                                     \
          if (kb0 + mt * 16 + r > (QG)) p[mt][r] = -3e38f;                                \
    }                                                                                     \
    float rm = p[0][0];                                                                   \
    _Pragma("unroll") for (int mt = 0; mt < 4; ++mt)                                      \
      _Pragma("unroll") for (int r = 0; r < 4; ++r) rm = fmaxf(rm, p[mt][r]);             \
    rm = fmaxf(rm, __shfl_xor(rm, 16));                                                   \
    rm = fmaxf(rm, __shfl_xor(rm, 32));                                                   \
    if (!__all(rm <= MST + 8.f)) { /* T13 defer-max */                                    \
      float mn = fmaxf(MST, rm);                                                          \
      float al = exp2f(MST - mn);                                                         \
      MST = mn;                                                                           \
      LST *= al;                                                                          \
      _Pragma("unroll") for (int ct = 0; ct < 4; ++ct)                                    \
        _Pragma("unroll") for (int r = 0; r < 4; ++r) OO[ct][r] *= al;                    \
    }                                                                                     \
    float rs = 0.f;                                                                       \
    _Pragma("unroll") for (int mt = 0; mt < 4; ++mt)                                      \
      _Pragma("unroll") for (int r = 0; r < 4; ++r) {                                     \
        p[mt][r] = exp2f(p[mt][r] - MST);                                                 \
        rs += p[mt][r];                                                                   \
      }                                                                                   \
    LST += rs;                                                                            \
    _Pragma("unroll") for (int mt = 0; mt < 4; ++mt) {                                    \
      ushortx4 uu;                                                                        \
      _Pragma("unroll") for (int r = 0; r < 4; ++r) uu[r] = f2bf_fast(p[mt][r]);          \
      int ch = (mt * 2 + (quad >> 1)) ^ (n16 & 7);                                        \
      *(ushortx4*)(&(SPW)[n16 * 64 + ch * 8 + (quad & 1) * 4]) = uu;                      \
    }                                                                                     \
  } while (0)

#define ACOMPUTE2(kt_, BUF)                                                               \
  do {                                                                                    \
    const unsigned short* kT_ = sKV + (BUF) * 8192;                                       \
    const unsigned short* vT_ = kT_ + 4096;                                               \
    f32x4 sc0[4], sc1[4];                                                                 \
    _Pragma("unroll") for (int mt = 0; mt < 4; ++mt) {                                    \
      const unsigned short* kr = &kT_[(mt * 16 + n16) * 64];                              \
      bf16x8 ka0 = *(const bf16x8*)(kr + ((quad ^ (n16 & 7)) * 8));                       \
      bf16x8 ka1 = *(const bf16x8*)(kr + (((4 + quad) ^ (n16 & 7)) * 8));                 \
      f32x4 z0 = f32x4{0.f, 0.f, 0.f, 0.f};                                               \
      z0 = __builtin_amdgcn_mfma_f32_16x16x32_bf16(ka0, aQ0[0], z0, 0, 0, 0);             \
      sc0[mt] = __builtin_amdgcn_mfma_f32_16x16x32_bf16(ka1, aQ0[1], z0, 0, 0, 0);        \
      f32x4 z1 = f32x4{0.f, 0.f, 0.f, 0.f};                                               \
      z1 = __builtin_amdgcn_mfma_f32_16x16x32_bf16(ka0, aQ1[0], z1, 0, 0, 0);             \
      sc1[mt] = __builtin_amdgcn_mfma_f32_16x16x32_bf16(ka1, aQ1[1], z1, 0, 0, 0);        \
    }                                                                                     \
    SOFTMAX_SUB(sc0, qg0, (kt_) >= nk - 2, mst0, lst0, o0, spW0);                         \
    SOFTMAX_SUB(sc1, qg1, (kt_) == nk - 1, mst1, lst1, o1, spW1);                         \
    __builtin_amdgcn_s_waitcnt(0xC07F); /* lgkmcnt(0); GLL prefetch stays in flight */    \
    bf16x8 aP00 = *(const bf16x8*)(&spW0[n16 * 64 + ((quad ^ (n16 & 7)) * 8)]);           \
    bf16x8 aP01 = *(const bf16x8*)(&spW0[n16 * 64 + (((4 + quad) ^ (n16 & 7)) * 8)]);     \
    bf16x8 aP10 = *(const bf16x8*)(&spW1[n16 * 64 + ((quad ^ (n16 & 7)) * 8)]);           \
    bf16x8 aP11 = *(const bf16x8*)(&spW1[n16 * 64 + (((4 + quad) ^ (n16 & 7)) * 8)]);     \
    _Pragma("unroll") for (int ct = 0; ct < 4; ++ct) {                                    \
      const unsigned short* vr = &vT_[(ct * 16 + n16) * 64];                              \
      bf16x8 va0 = *(const bf16x8*)(vr + ((quad ^ (n16 & 7)) * 8));                       \
      bf16x8 va1 = *(const bf16x8*)(vr + (((4 + quad) ^ (n16 & 7)) * 8));                 \
      o0[ct] = __builtin_amdgcn_mfma_f32_16x16x32_bf16(va0, aP00, o0[ct], 0, 0, 0);       \
      o0[ct] = __builtin_amdgcn_mfma_f32_16x16x32_bf16(va1, aP01, o0[ct], 0, 0, 0);       \
      o1[ct] = __builtin_amdgcn_mfma_f32_16x16x32_bf16(va0, aP10, o1[ct], 0, 0, 0);       \
      o1[ct] = __builtin_amdgcn_mfma_f32_16x16x32_bf16(va1, aP11, o1[ct], 0, 0, 0);       \
    }                                                                                     \
  } while (0)

  ASTAGE(0, 0);
  int it = 0;
  while (it < nk) {
    __syncthreads();  // drains loads into buf0 (nk is block-uniform)
    {
      int kt_ = it;
      if (kt_ + 1 < nk) ASTAGE(kt_ + 1, 1);
      ACOMPUTE2(kt_, 0);
    }
    if (++it >= nk) break;
    __syncthreads();  // drains loads into buf1
    {
      int kt_ = it;
      if (kt_ + 1 < nk) ASTAGE(kt_ + 1, 0);
      ACOMPUTE2(kt_, 1);
    }
    ++it;
  }
#undef ASTAGE
#undef SOFTMAX_SUB
#undef ACOMPUTE2

  // finish lane-partial l (cross-quad k-partials) and write both sub-blocks
  lst0 += __shfl_xor(lst0, 16);
  lst0 += __shfl_xor(lst0, 32);
  lst1 += __shfl_xor(lst1, 16);
  lst1 += __shfl_xor(lst1, 32);
  float inv0 = 1.0f / lst0, inv1 = 1.0f / lst1;
#pragma unroll
  for (int ct = 0; ct < 4; ++ct) {
    ushortx4 u0, u1;
#pragma unroll
    for (int r = 0; r < 4; ++r) {
      u0[r] = f2bf(o0[ct][r] * inv0);
      u1[r] = f2bf(o1[ct][r] * inv1);
    }
    size_t a0 = ((size_t)b_ * 2048 + qg0) * 1024 + h_ * 64 + ct * 16 + quad * 4;
    size_t a1 = ((size_t)b_ * 2048 + qg1) * 1024 + h_ * 64 + ct * 16 + quad * 4;
    *(ushortx4*)(&O[a0]) = u0;
    *(ushortx4*)(&O[a1]) = u1;
  }
}

// ---------------- launch ----------------
extern "C" void kernel_launch(void* const* d_in, const int* in_sizes, int n_in,
                              void* d_out, int out_size, void* d_ws, size_t ws_size,
                              hipStream_t stream) {
  const float* X    = (const float*)d_in[0];
  const int*   pos  = (const int*)d_in[2];
  const float* cosb = (const float*)d_in[3];
  const float* sinb = (const float*)d_in[4];
  const float* Wq   = (const float*)d_in[5];
  const float* Wk   = (const float*)d_in[6];
  const float* Wv   = (const float*)d_in[7];
  const float* Wo   = (const float*)d_in[8];
  float* out = (float*)d_out;

  char* ws = (char*)d_ws;
  const size_t SZ_X = 4096UL * 1024 * 2;
  const size_t SZ_W = 1024UL * 1024 * 2;
  unsigned short* Xbf = (unsigned short*)(ws);
  unsigned short* WTq = (unsigned short*)(ws + SZ_X);
  unsigned short* WTk = (unsigned short*)(ws + SZ_X + SZ_W);
  unsigned short* WTv = (unsigned short*)(ws + SZ_X + 2 * SZ_W);
  unsigned short* WTo = (unsigned short*)(ws + SZ_X + 3 * SZ_W);
  unsigned short* Qbf = (unsigned short*)(ws + SZ_X + 4 * SZ_W);
  unsigned short* Kbf = (unsigned short*)(ws + 2 * SZ_X + 4 * SZ_W);
  unsigned short* VTr = (unsigned short*)(ws + 3 * SZ_X + 4 * SZ_W);
  unsigned short* Obf = (unsigned short*)(ws + 4 * SZ_X + 4 * SZ_W);

  prep_kernel<<<dim3(32, 32, 6), dim3(32, 8), 0, stream>>>(
      X, Wq, Wk, Wv, Wo, Xbf, WTq, WTk, WTv, WTo);

  // QKV projections + fused RoPE (Q pre-scaled) + fused V-transpose, 128^2 ring
  qkvr_kernel<<<dim3(8, 32, 3), 256, 0, stream>>>(Xbf, WTq, WTk, WTv,
                                                  Qbf, Kbf, VTr,
                                                  pos, cosb, sinb);

  // attention: 4-wave blocks, q-tile 128 (2 sub-blocks/wave), 48KB LDS
  attn_kernel<<<dim3(32, 16), 256, 0, stream>>>(Qbf, Kbf, VTr, Obf);

  // Wo GEMM: 128x64 ring, 512 blocks
  wor_kernel<<<dim3(8, 64), 256, 0, stream>>>(Obf, WTo, out);
}

// Round 11
// 201.240 us; speedup vs baseline: 1.0725x; 1.0725x over previous
//
#include <hip/hip_runtime.h>

typedef __bf16 bf16x8 __attribute__((ext_vector_type(8)));
typedef float  f32x4  __attribute__((ext_vector_type(4)));
typedef unsigned short ushortx8 __attribute__((ext_vector_type(8)));
typedef unsigned short ushortx4 __attribute__((ext_vector_type(4)));

static __device__ __forceinline__ unsigned short f2bf(float f) {
  unsigned int u = __builtin_bit_cast(unsigned int, f);
  u += 0x7FFFu + ((u >> 16) & 1u);
  return (unsigned short)(u >> 16);
}
static __device__ __forceinline__ unsigned short f2bf_fast(float f) {  // round-half-up
  unsigned int u = __builtin_bit_cast(unsigned int, f);
  return (unsigned short)((u + 0x8000u) >> 16);
}

#define GLL16(gp, lp) __builtin_amdgcn_global_load_lds(                       \
    (const __attribute__((address_space(1))) void*)(gp),                      \
    (__attribute__((address_space(3))) void*)(lp), 16, 0, 0)

// ---------------- prep: z<4 -> transpose+cast W; z>=4 -> cast X fp32->bf16 ----------------
__global__ __launch_bounds__(256) void prep_kernel(const float* __restrict__ X,
                                                   const float* __restrict__ W0,
                                                   const float* __restrict__ W1,
                                                   const float* __restrict__ W2,
                                                   const float* __restrict__ W3,
                                                   unsigned short* __restrict__ Xbf,
                                                   unsigned short* __restrict__ D0,
                                                   unsigned short* __restrict__ D1,
                                                   unsigned short* __restrict__ D2,
                                                   unsigned short* __restrict__ D3) {
  int z = blockIdx.z;
  if (z >= 4) {  // cast 4096x1024 fp32 -> bf16; z in {4,5}
    long bid = (long)(z - 4) * 1024 + blockIdx.y * 32 + blockIdx.x;
    int tl = threadIdx.y * 32 + threadIdx.x;
    long i = bid * 2048 + (long)tl * 8;
    float4 f0 = *(const float4*)(X + i);
    float4 f1 = *(const float4*)(X + i + 4);
    ushortx8 u;
    u[0] = f2bf(f0.x); u[1] = f2bf(f0.y); u[2] = f2bf(f0.z); u[3] = f2bf(f0.w);
    u[4] = f2bf(f1.x); u[5] = f2bf(f1.y); u[6] = f2bf(f1.z); u[7] = f2bf(f1.w);
    *(ushortx8*)(Xbf + i) = u;
    return;
  }
  const float* src = (z == 0) ? W0 : (z == 1) ? W1 : (z == 2) ? W2 : W3;
  unsigned short* dst = (z == 0) ? D0 : (z == 1) ? D1 : (z == 2) ? D2 : D3;
  const int R = 1024, C = 1024;
  __shared__ unsigned short t[32][33];
  int c = blockIdx.x * 32 + threadIdx.x;
#pragma unroll
  for (int i = 0; i < 4; ++i) {
    int r = blockIdx.y * 32 + threadIdx.y + i * 8;
    t[threadIdx.y + i * 8][threadIdx.x] = f2bf(src[(size_t)r * C + c]);
  }
  __syncthreads();
  int rr = blockIdx.y * 32 + threadIdx.x;
#pragma unroll
  for (int i = 0; i < 4; ++i) {
    int cc = blockIdx.x * 32 + threadIdx.y + i * 8;
    dst[(size_t)cc * R + rr] = t[threadIdx.x][threadIdx.y + i * 8];
  }
}

// ---------------- QKV GEMM: 128x128 tile, BK=32, 3-deep LDS ring, counted vmcnt ----
// 48KB LDS -> 3 blocks/CU residency (TLP hides the counted wait). 4 loads/thread/tile,
// prefetch distance 2. Trailing vmcnt(4). z: 0=Q (RoPE, pre-scaled), 1=K (RoPE), 2=V^T.
__global__ __launch_bounds__(256, 3) void qkvr_kernel(
    const unsigned short* __restrict__ A,
    const unsigned short* __restrict__ BT0,
    const unsigned short* __restrict__ BT1,
    const unsigned short* __restrict__ BT2,
    unsigned short* __restrict__ outQ,
    unsigned short* __restrict__ outK,
    unsigned short* __restrict__ outVT,
    const int* __restrict__ pos_ids,
    const float* __restrict__ cosb,
    const float* __restrict__ sinb) {
  const int K = 1024;
  int id = blockIdx.x + 8 * (blockIdx.y + 32 * blockIdx.z);
  int m_idx = id & 31;         // m fastest => xcd = id%8 = m_idx%8
  int nzi = id >> 5;
  int n_idx = nzi & 7;
  int z = nzi >> 3;
  const unsigned short* BT = (z == 0) ? BT0 : (z == 1 ? BT1 : BT2);
  int n0 = n_idx * 128, m0 = m_idx * 128;
  int t = threadIdx.x, lane = t & 63, w = t >> 6;
  int wy = w >> 1, wx = w & 1;
  int n16 = lane & 15, quad = lane >> 4;

  __shared__ __align__(16) unsigned short sA[3][128][32];
  __shared__ __align__(16) unsigned short sB[3][128][32];
  __shared__ __align__(16) unsigned short sDummy[512];  // tail sink (never read)
  const int BUFE = 128 * 32;

  int r4 = lane >> 2, c4 = lane & 3;
  const char* gA = (const char*)(A + (size_t)(m0 + w * 32 + r4) * K) + ((c4 ^ (r4 & 3)) * 16);
  const char* gB = (const char*)(BT + (size_t)(n0 + w * 32 + r4) * K) + ((c4 ^ (r4 & 3)) * 16);
  const size_t row16 = (size_t)16 * K * 2;
  unsigned short* stA = &sA[0][w * 32][0];
  unsigned short* stB = &sB[0][w * 32][0];

  int cs = (quad ^ (n16 & 3)) * 8;
  const unsigned short* rdA = &sA[0][wy * 64 + n16][0] + cs;
  const unsigned short* rdB = &sB[0][wx * 64 + n16][0] + cs;

  f32x4 acc[4][4];
#pragma unroll
  for (int i = 0; i < 4; ++i)
#pragma unroll
    for (int j = 0; j < 4; ++j) acc[i][j] = f32x4{0.f, 0.f, 0.f, 0.f};

  bf16x8 a[4], b[4];

#define QSTG(tt, dA, dB)                                                        \
  do {                                                                          \
    GLL16(gA + (size_t)(tt) * 64, (dA));                                        \
    GLL16(gA + (size_t)(tt) * 64 + row16, (dA) + 16 * 32);                      \
    GLL16(gB + (size_t)(tt) * 64, (dB));                                        \
    GLL16(gB + (size_t)(tt) * 64 + row16, (dB) + 16 * 32);                      \
  } while (0)

#define QRD(bufi)                                                               \
  do {                                                                          \
    _Pragma("unroll") for (int i = 0; i < 4; ++i) {                             \
      a[i] = *(const bf16x8*)(rdA + (bufi) * BUFE + (i * 16) * 32);             \
      b[i] = *(const bf16x8*)(rdB + (bufi) * BUFE + (i * 16) * 32);             \
    }                                                                           \
  } while (0)

#define QMM                                                                     \
  do {                                                                          \
    _Pragma("unroll") for (int mt = 0; mt < 4; ++mt)                            \
      _Pragma("unroll") for (int nt = 0; nt < 4; ++nt)                          \
        acc[mt][nt] = __builtin_amdgcn_mfma_f32_16x16x32_bf16(                  \
            a[mt], b[nt], acc[mt][nt], 0, 0, 0);                                \
  } while (0)

  // prologue: stage tiles 0,1 (8 loads); vmcnt(4) -> tile0 landed, tile1 in flight
  QSTG(0, stA, stB);
  QSTG(1, stA + BUFE, stB + BUFE);
  asm volatile("s_waitcnt vmcnt(4)" ::: "memory");
  __builtin_amdgcn_s_barrier();

#pragma unroll 3
  for (int kt = 0; kt < 30; ++kt) {
    int buf = kt % 3;
    int pfb = (kt + 2) % 3;
    QRD(buf);
    QSTG(kt + 2, stA + pfb * BUFE, stB + pfb * BUFE);
    QMM;
    asm volatile("s_waitcnt vmcnt(4)" ::: "memory");
    __builtin_amdgcn_s_barrier();
  }
  // tail: tiles 30 (buf 0) and 31 (buf 1); dummy staging keeps vmcnt uniform
  {
    QRD(0);
    QSTG(31, sDummy, sDummy);  // addresses valid (tile31 global), dest is sink
    QMM;
    asm volatile("s_waitcnt vmcnt(4)" ::: "memory");
    __builtin_amdgcn_s_barrier();
  }
  {
    QRD(1);
    QSTG(31, sDummy, sDummy);
    QMM;
    asm volatile("s_waitcnt vmcnt(0)" ::: "memory");  // drain sinks before epilogue
  }
#undef QSTG
#undef QRD
#undef QMM

  if (z < 2) {  // fused RoPE on Q/K; Q additionally pre-scaled by SCALE*log2(e)
    const float qs = (z == 0) ? (0.125f * 1.44269504088896340736f) : 1.0f;
#pragma unroll
    for (int mt = 0; mt < 4; ++mt)
#pragma unroll
      for (int r = 0; r < 4; ++r) {
        int row = m0 + wy * 64 + mt * 16 + quad * 4 + r;
        int b_ = row >> 11, s_ = row & 2047;
        int pos = pos_ids[b_ * 2048 + s_];
        const float* cb = cosb + (size_t)pos * 64;
        const float* sb = sinb + (size_t)pos * 64;
#pragma unroll
        for (int nt = 0; nt < 2; ++nt) {
          int d0 = nt * 16 + n16;
          float c0 = cb[d0] * qs, s0 = sb[d0] * qs;
          float c1 = cb[d0 + 32] * qs, s1 = sb[d0 + 32] * qs;
          float x0 = acc[mt][nt][r], x1 = acc[mt][nt + 2][r];
          acc[mt][nt][r]     = x0 * c0 - x1 * s0;
          acc[mt][nt + 2][r] = x1 * c1 + x0 * s1;
        }
      }
    unsigned short* dst = (z == 0) ? outQ : outK;
#pragma unroll
    for (int mt = 0; mt < 4; ++mt)
#pragma unroll
      for (int nt = 0; nt < 4; ++nt)
#pragma unroll
        for (int r = 0; r < 4; ++r) {
          int row = m0 + wy * 64 + mt * 16 + quad * 4 + r;
          int col = n0 + wx * 64 + nt * 16 + n16;
          int b_ = row >> 11, s_ = row & 2047, h_ = col >> 6, d_ = col & 63;
          dst[(((size_t)b_ * 16 + h_) * 2048 + s_) * 64 + d_] = f2bf(acc[mt][nt][r]);
        }
    return;
  }

  // z == 2: V^T fused write: VT[((b*16+h)*64+d)*2048 + s]; 4 consecutive s per lane
#pragma unroll
  for (int mt = 0; mt < 4; ++mt)
#pragma unroll
    for (int nt = 0; nt < 4; ++nt) {
      int row = m0 + wy * 64 + mt * 16 + quad * 4;  // +r stays within one b
      int b_ = row >> 11, s_ = row & 2047;
      int col = n0 + wx * 64 + nt * 16 + n16;
      int h_ = col >> 6, d_ = col & 63;
      ushortx4 u;
#pragma unroll
      for (int r = 0; r < 4; ++r) u[r] = f2bf(acc[mt][nt][r]);
      *(ushortx4*)(&outVT[(((size_t)b_ * 16 + h_) * 64 + d_) * 2048 + s_]) = u;
    }
}

// ---------------- Wo GEMM: 128x64 tile, BK=32, 3-deep ring, counted vmcnt ----
// M=4096 x N=1024 -> 512 blocks (2/CU). id = bx + 8*by, m fastest -> xcd = m%8
// (A-panels L2-pinned per XCD). 3 loads/thread/tile (2A+1B) -> trailing vmcnt(3).
__global__ __launch_bounds__(256) void wor_kernel(const unsigned short* __restrict__ A,
                                                  const unsigned short* __restrict__ BT,
                                                  float* __restrict__ outF) {
  const int K = 1024, N = 1024;
  int id = blockIdx.x + 8 * blockIdx.y;  // grid (8,64)
  int m_idx = id & 31, n_idx = id >> 5;
  int m0 = m_idx * 128, n0 = n_idx * 64;
  int t = threadIdx.x, lane = t & 63, w = t >> 6;
  int wy = w >> 1, wx = w & 1;
  int n16 = lane & 15, quad = lane >> 4;

  __shared__ __align__(16) unsigned short sA[3][128][32];
  __shared__ __align__(16) unsigned short sB[3][64][32];
  __shared__ __align__(16) unsigned short sDummy[512];
  const int BUFA = 128 * 32, BUFB = 64 * 32;

  int r4 = lane >> 2, c4 = lane & 3;
  const char* gA = (const char*)(A + (size_t)(m0 + w * 32 + r4) * K) + ((c4 ^ (r4 & 3)) * 16);
  const char* gB = (const char*)(BT + (size_t)(n0 + w * 16 + r4) * K) + ((c4 ^ (r4 & 3)) * 16);
  const size_t row16 = (size_t)16 * K * 2;
  unsigned short* stA = &sA[0][w * 32][0];
  unsigned short* stB = &sB[0][w * 16][0];

  int cs = (quad ^ (n16 & 3)) * 8;
  const unsigned short* rdA = &sA[0][wy * 64 + n16][0] + cs;
  const unsigned short* rdB = &sB[0][wx * 32 + n16][0] + cs;

  f32x4 acc[4][2];
#pragma unroll
  for (int i = 0; i < 4; ++i)
#pragma unroll
    for (int j = 0; j < 2; ++j) acc[i][j] = f32x4{0.f, 0.f, 0.f, 0.f};

  bf16x8 a[4], b[2];

#define WSTG(tt, dA, dB)                                                        \
  do {                                                                          \
    GLL16(gA + (size_t)(tt) * 64, (dA));                                        \
    GLL16(gA + (size_t)(tt) * 64 + row16, (dA) + 16 * 32);                      \
    GLL16(gB + (size_t)(tt) * 64, (dB));                                        \
  } while (0)

#define WRD(bufi)                                                               \
  do {                                                                          \
    _Pragma("unroll") for (int i = 0; i < 4; ++i)                               \
      a[i] = *(const bf16x8*)(rdA + (bufi) * BUFA + (i * 16) * 32);             \
    _Pragma("unroll") for (int j = 0; j < 2; ++j)                               \
      b[j] = *(const bf16x8*)(rdB + (bufi) * BUFB + (j * 16) * 32);             \
  } while (0)

#define WMM                                                                     \
  do {                                                                          \
    _Pragma("unroll") for (int mt = 0; mt < 4; ++mt)                            \
      _Pragma("unroll") for (int nt = 0; nt < 2; ++nt)                          \
        acc[mt][nt] = __builtin_amdgcn_mfma_f32_16x16x32_bf16(                  \
            a[mt], b[nt], acc[mt][nt], 0, 0, 0);                                \
  } while (0)

  WSTG(0, stA, stB);
  WSTG(1, stA + BUFA, stB + BUFB);
  asm volatile("s_waitcnt vmcnt(3)" ::: "memory");
  __builtin_amdgcn_s_barrier();

#pragma unroll 3
  for (int kt = 0; kt < 30; ++kt) {
    int buf = kt % 3;
    int pfb = (kt + 2) % 3;
    WRD(buf);
    WSTG(kt + 2, stA + pfb * BUFA, stB + pfb * BUFB);
    WMM;
    asm volatile("s_waitcnt vmcnt(3)" ::: "memory");
    __builtin_amdgcn_s_barrier();
  }
  {
    WRD(0);
    WSTG(31, sDummy, sDummy);
    WMM;
    asm volatile("s_waitcnt vmcnt(3)" ::: "memory");
    __builtin_amdgcn_s_barrier();
  }
  {
    WRD(1);
    WSTG(31, sDummy, sDummy);
    WMM;
    asm volatile("s_waitcnt vmcnt(0)" ::: "memory");
  }
#undef WSTG
#undef WRD
#undef WMM

#pragma unroll
  for (int mt = 0; mt < 4; ++mt)
#pragma unroll
    for (int nt = 0; nt < 2; ++nt)
#pragma unroll
      for (int r = 0; r < 4; ++r) {
        int row = m0 + wy * 64 + mt * 16 + quad * 4 + r;
        int col = n0 + wx * 32 + nt * 16 + n16;
        outF[(size_t)row * N + col] = acc[mt][nt][r];
      }
}

// ---------------- Flash attention: 4 waves, NO split-k, 40KB LDS (R9-proven) ----
// R11 deltas vs R9: (1) T5 setprio(1) around the QK^T and PV MFMA clusters (m191-regime:
// multiple independent blocks/CU at different tiles -> wave-phase diversity); (2) V
// fragments hoisted above softmax (V buffer valid since phase barrier; overlaps LDS
// latency under the VALU chain).
__global__ __launch_bounds__(256) void attn_kernel(const unsigned short* __restrict__ Q,
                                                   const unsigned short* __restrict__ Kk,
                                                   const unsigned short* __restrict__ VT,
                                                   unsigned short* __restrict__ O) {
  int bh = blockIdx.x;
  int qt = (int)(gridDim.y - 1 - blockIdx.y);  // LPT
  int t = threadIdx.x;
  int lane = t & 63;
  int w = t >> 6;          // 0..3
  int n16 = lane & 15, quad = lane >> 4;
  int r8 = lane >> 3, c8 = lane & 7;
  const unsigned short* Qb = Q + (size_t)bh * 2048 * 64;
  const unsigned short* Kb = Kk + (size_t)bh * 2048 * 64;
  const unsigned short* Vb = VT + (size_t)bh * 64 * 2048;

  __shared__ __align__(16) unsigned short sKV[2 * 8192];  // [buf][K 4096 | V 4096]
  __shared__ __align__(16) unsigned short sP[4][16 * 64];
  unsigned short* spW = sP[w];

  int b_ = bh >> 4, h_ = bh & 15;
  int nk = qt + 1;
  int qg = qt * 64 + w * 16 + n16;  // this lane's q-row

  bf16x8 aQ[2];
#pragma unroll
  for (int kb = 0; kb < 2; ++kb)
    aQ[kb] = *(const bf16x8*)(Qb + (size_t)qg * 64 + kb * 32 + quad * 8);

  f32x4 o[4];
  float mst = -3e38f, lst = 0.f;
#pragma unroll
  for (int ct = 0; ct < 4; ++ct) o[ct] = f32x4{0.f, 0.f, 0.f, 0.f};

#define ASTAGE(kt_, BUF)                                                                  \
  do {                                                                                    \
    const unsigned short* kg_ = Kb + (size_t)((kt_) * 64 + w * 16) * 64;                  \
    const unsigned short* vg_ = Vb + (size_t)(w * 16) * 2048 + (kt_) * 64;                \
    unsigned short* dK = sKV + (BUF) * 8192 + (w * 16) * 64;                              \
    unsigned short* dV = dK + 4096;                                                       \
    GLL16(kg_ + (size_t)r8 * 64 + (c8 ^ r8) * 8, dK);                                     \
    GLL16(kg_ + (size_t)(8 + r8) * 64 + (c8 ^ r8) * 8, dK + 8 * 64);                      \
    GLL16(vg_ + (size_t)r8 * 2048 + (c8 ^ r8) * 8, dV);                                   \
    GLL16(vg_ + (size_t)(8 + r8) * 2048 + (c8 ^ r8) * 8, dV + 8 * 64);                    \
  } while (0)

#define ACOMPUTE(kt_, BUF)                                                                \
  do {                                                                                    \
    const unsigned short* kT_ = sKV + (BUF) * 8192;                                       \
    const unsigned short* vT_ = kT_ + 4096;                                               \
    f32x4 sc[4]; /* S^T: D[m=k][n=q], A=K-frag, B=Q-frag */                               \
    __builtin_amdgcn_s_setprio(1);                                                        \
    _Pragma("unroll") for (int mt = 0; mt < 4; ++mt) {                                    \
      const unsigned short* kr = &kT_[(mt * 16 + n16) * 64];                              \
      bf16x8 ka0 = *(const bf16x8*)(kr + ((quad ^ (n16 & 7)) * 8));                       \
      bf16x8 ka1 = *(const bf16x8*)(kr + (((4 + quad) ^ (n16 & 7)) * 8));                 \
      f32x4 zv = f32x4{0.f, 0.f, 0.f, 0.f};                                               \
      zv = __builtin_amdgcn_mfma_f32_16x16x32_bf16(ka0, aQ[0], zv, 0, 0, 0);              \
      sc[mt] = __builtin_amdgcn_mfma_f32_16x16x32_bf16(ka1, aQ[1], zv, 0, 0, 0);          \
    }                                                                                     \
    __builtin_amdgcn_s_setprio(0);                                                        \
    /* V-hoist: buffer valid since phase barrier; overlap LDS latency under softmax */    \
    bf16x8 va0[4], va1[4];                                                                \
    _Pragma("unroll") for (int ct = 0; ct < 4; ++ct) {                                    \
      const unsigned short* vr = &vT_[(ct * 16 + n16) * 64];                              \
      va0[ct] = *(const bf16x8*)(vr + ((quad ^ (n16 & 7)) * 8));                          \
      va1[ct] = *(const bf16x8*)(vr + (((4 + quad) ^ (n16 & 7)) * 8));                    \
    }                                                                                     \
    float p[4][4];                                                                        \
    _Pragma("unroll") for (int mt = 0; mt < 4; ++mt)                                      \
      _Pragma("unroll") for (int r = 0; r < 4; ++r) p[mt][r] = sc[mt][r];                 \
    if ((kt_) == nk - 1) { /* diagonal tile: mask k > q */                                \
      int kb0 = (kt_) * 64 + quad * 4;                                                    \
      _Pragma("unroll") for (int mt = 0; mt < 4; ++mt)                                    \
        _Pragma("unroll") for (int r = 0; r < 4; ++r)                                     \
          if (kb0 + mt * 16 + r > qg) p[mt][r] = -3e38f;                                  \
    }                                                                                     \
    float rm = p[0][0];                                                                   \
    _Pragma("unroll") for (int mt = 0; mt < 4; ++mt)                                      \
      _Pragma("unroll") for (int r = 0; r < 4; ++r) rm = fmaxf(rm, p[mt][r]);             \
    rm = fmaxf(rm, __shfl_xor(rm, 16));                                                   \
    rm = fmaxf(rm, __shfl_xor(rm, 32));                                                   \
    if (!__all(rm <= mst + 8.f)) { /* T13 defer-max: rescale only on real growth */       \
      float mn = fmaxf(mst, rm);                                                          \
      float al = exp2f(mst - mn);                                                         \
      mst = mn;                                                                           \
      lst *= al;                                                                          \
      _Pragma("unroll") for (int ct = 0; ct < 4; ++ct)                                    \
        _Pragma("unroll") for (int r = 0; r < 4; ++r) o[ct][r] *= al;                     \
    }                                                                                     \
    float rs = 0.f;                                                                       \
    _Pragma("unroll") for (int mt = 0; mt < 4; ++mt)                                      \
      _Pragma("unroll") for (int r = 0; r < 4; ++r) {                                     \
        p[mt][r] = exp2f(p[mt][r] - mst);                                                 \
        rs += p[mt][r];                                                                   \
      }                                                                                   \
    lst += rs;                                                                            \
    _Pragma("unroll") for (int mt = 0; mt < 4; ++mt) {                                    \
      ushortx4 uu;                                                                        \
      _Pragma("unroll") for (int r = 0; r < 4; ++r) uu[r] = f2bf_fast(p[mt][r]);          \
      int ch = (mt * 2 + (quad >> 1)) ^ (n16 & 7);                                        \
      *(ushortx4*)(&spW[n16 * 64 + ch * 8 + (quad & 1) * 4]) = uu;                        \
    }                                                                                     \
    __builtin_amdgcn_s_waitcnt(0xC07F); /* lgkmcnt(0); GLL prefetch stays in flight */    \
    bf16x8 aP0 = *(const bf16x8*)(&spW[n16 * 64 + ((quad ^ (n16 & 7)) * 8)]);             \
    bf16x8 aP1 = *(const bf16x8*)(&spW[n16 * 64 + (((4 + quad) ^ (n16 & 7)) * 8)]);       \
    __builtin_amdgcn_s_setprio(1);                                                        \
    _Pragma("unroll") for (int ct = 0; ct < 4; ++ct) {                                    \
      o[ct] = __builtin_amdgcn_mfma_f32_16x16x32_bf16(va0[ct], aP0, o[ct], 0, 0, 0);      \
      o[ct] = __builtin_amdgcn_mfma_f32_16x16x32_bf16(va1[ct], aP1, o[ct], 0, 0, 0);      \
    }                                                                                     \
    __builtin_amdgcn_s_setprio(0);                                                        \
  } while (0)

  ASTAGE(0, 0);
  int it = 0;
  while (it < nk) {
    __syncthreads();  // drains loads into buf0 (nk is block-uniform)
    {
      int kt = it;
      if (kt + 1 < nk) ASTAGE(kt + 1, 1);
      ACOMPUTE(kt, 0);
    }
    if (++it >= nk) break;
    __syncthreads();  // drains loads into buf1
    {
      int kt = it;
      if (kt + 1 < nk) ASTAGE(kt + 1, 0);
      ACOMPUTE(kt, 1);
    }
    ++it;
  }
#undef ASTAGE
#undef ACOMPUTE

  // finish lane-partial l (cross-quad k-partials) and write output
  lst += __shfl_xor(lst, 16);
  lst += __shfl_xor(lst, 32);
  float inv = 1.0f / lst;
#pragma unroll
  for (int ct = 0; ct < 4; ++ct) {
    ushortx4 uo;
#pragma unroll
    for (int r = 0; r < 4; ++r) uo[r] = f2bf(o[ct][r] * inv);
    size_t addr = ((size_t)b_ * 2048 + qg) * 1024 + h_ * 64 + ct * 16 + quad * 4;
    *(ushortx4*)(&O[addr]) = uo;
  }
}

// ---------------- launch ----------------
extern "C" void kernel_launch(void* const* d_in, const int* in_sizes, int n_in,
                              void* d_out, int out_size, void* d_ws, size_t ws_size,
                              hipStream_t stream) {
  const float* X    = (const float*)d_in[0];
  const int*   pos  = (const int*)d_in[2];
  const float* cosb = (const float*)d_in[3];
  const float* sinb = (const float*)d_in[4];
  const float* Wq   = (const float*)d_in[5];
  const float* Wk   = (const float*)d_in[6];
  const float* Wv   = (const float*)d_in[7];
  const float* Wo   = (const float*)d_in[8];
  float* out = (float*)d_out;

  char* ws = (char*)d_ws;
  const size_t SZ_X = 4096UL * 1024 * 2;
  const size_t SZ_W = 1024UL * 1024 * 2;
  unsigned short* Xbf = (unsigned short*)(ws);
  unsigned short* WTq = (unsigned short*)(ws + SZ_X);
  unsigned short* WTk = (unsigned short*)(ws + SZ_X + SZ_W);
  unsigned short* WTv = (unsigned short*)(ws + SZ_X + 2 * SZ_W);
  unsigned short* WTo = (unsigned short*)(ws + SZ_X + 3 * SZ_W);
  unsigned short* Qbf = (unsigned short*)(ws + SZ_X + 4 * SZ_W);
  unsigned short* Kbf = (unsigned short*)(ws + 2 * SZ_X + 4 * SZ_W);
  unsigned short* VTr = (unsigned short*)(ws + 3 * SZ_X + 4 * SZ_W);
  unsigned short* Obf = (unsigned short*)(ws + 4 * SZ_X + 4 * SZ_W);

  prep_kernel<<<dim3(32, 32, 6), dim3(32, 8), 0, stream>>>(
      X, Wq, Wk, Wv, Wo, Xbf, WTq, WTk, WTv, WTo);

  // QKV projections + fused RoPE (Q pre-scaled) + fused V-transpose, 128^2 ring
  qkvr_kernel<<<dim3(8, 32, 3), 256, 0, stream>>>(Xbf, WTq, WTk, WTv,
                                                  Qbf, Kbf, VTr,
                                                  pos, cosb, sinb);

  // attention: 4-wave blocks, 40KB LDS, setprio + V-hoist
  attn_kernel<<<dim3(32, 32), 256, 0, stream>>>(Qbf, Kbf, VTr, Obf);

  // Wo GEMM: 128x64 ring, 512 blocks
  wor_kernel<<<dim3(8, 64), 256, 0, stream>>>(Obf, WTo, out);
}

// Round 12
// 199.530 us; speedup vs baseline: 1.0817x; 1.0086x over previous
//
#include <hip/hip_runtime.h>

typedef __bf16 bf16x8 __attribute__((ext_vector_type(8)));
typedef __bf16 bf16x4 __attribute__((ext_vector_type(4)));
typedef float  f32x4  __attribute__((ext_vector_type(4)));
typedef unsigned short ushortx8 __attribute__((ext_vector_type(8)));
typedef unsigned short ushortx4 __attribute__((ext_vector_type(4)));

static __device__ __forceinline__ unsigned short f2bf(float f) {
  unsigned int u = __builtin_bit_cast(unsigned int, f);
  u += 0x7FFFu + ((u >> 16) & 1u);
  return (unsigned short)(u >> 16);
}

#define GLL16(gp, lp) __builtin_amdgcn_global_load_lds(                       \
    (const __attribute__((address_space(1))) void*)(gp),                      \
    (__attribute__((address_space(3))) void*)(lp), 16, 0, 0)

// ---------------- prep: z<4 -> transpose+cast W; z>=4 -> cast X fp32->bf16 ----------------
__global__ __launch_bounds__(256) void prep_kernel(const float* __restrict__ X,
                                                   const float* __restrict__ W0,
                                                   const float* __restrict__ W1,
                                                   const float* __restrict__ W2,
                                                   const float* __restrict__ W3,
                                                   unsigned short* __restrict__ Xbf,
                                                   unsigned short* __restrict__ D0,
                                                   unsigned short* __restrict__ D1,
                                                   unsigned short* __restrict__ D2,
                                                   unsigned short* __restrict__ D3) {
  int z = blockIdx.z;
  if (z >= 4) {  // cast 4096x1024 fp32 -> bf16; z in {4,5}
    long bid = (long)(z - 4) * 1024 + blockIdx.y * 32 + blockIdx.x;
    int tl = threadIdx.y * 32 + threadIdx.x;
    long i = bid * 2048 + (long)tl * 8;
    float4 f0 = *(const float4*)(X + i);
    float4 f1 = *(const float4*)(X + i + 4);
    ushortx8 u;
    u[0] = f2bf(f0.x); u[1] = f2bf(f0.y); u[2] = f2bf(f0.z); u[3] = f2bf(f0.w);
    u[4] = f2bf(f1.x); u[5] = f2bf(f1.y); u[6] = f2bf(f1.z); u[7] = f2bf(f1.w);
    *(ushortx8*)(Xbf + i) = u;
    return;
  }
  const float* src = (z == 0) ? W0 : (z == 1) ? W1 : (z == 2) ? W2 : W3;
  unsigned short* dst = (z == 0) ? D0 : (z == 1) ? D1 : (z == 2) ? D2 : D3;
  const int R = 1024, C = 1024;
  __shared__ unsigned short t[32][33];
  int c = blockIdx.x * 32 + threadIdx.x;
#pragma unroll
  for (int i = 0; i < 4; ++i) {
    int r = blockIdx.y * 32 + threadIdx.y + i * 8;
    t[threadIdx.y + i * 8][threadIdx.x] = f2bf(src[(size_t)r * C + c]);
  }
  __syncthreads();
  int rr = blockIdx.y * 32 + threadIdx.x;
#pragma unroll
  for (int i = 0; i < 4; ++i) {
    int cc = blockIdx.x * 32 + threadIdx.y + i * 8;
    dst[(size_t)cc * R + rr] = t[threadIdx.x][threadIdx.y + i * 8];
  }
}

// ---------------- QKV GEMM: 128x128 tile, BK=32, 3-deep LDS ring, counted vmcnt ----
// 48KB LDS -> 3 blocks/CU residency (TLP hides the counted wait). 4 loads/thread/tile,
// prefetch distance 2. Trailing vmcnt(4). z: 0=Q (RoPE, pre-scaled), 1=K (RoPE), 2=V^T.
__global__ __launch_bounds__(256, 3) void qkvr_kernel(
    const unsigned short* __restrict__ A,
    const unsigned short* __restrict__ BT0,
    const unsigned short* __restrict__ BT1,
    const unsigned short* __restrict__ BT2,
    unsigned short* __restrict__ outQ,
    unsigned short* __restrict__ outK,
    unsigned short* __restrict__ outVT,
    const int* __restrict__ pos_ids,
    const float* __restrict__ cosb,
    const float* __restrict__ sinb) {
  const int K = 1024;
  int id = blockIdx.x + 8 * (blockIdx.y + 32 * blockIdx.z);
  int m_idx = id & 31;         // m fastest => xcd = id%8 = m_idx%8
  int nzi = id >> 5;
  int n_idx = nzi & 7;
  int z = nzi >> 3;
  const unsigned short* BT = (z == 0) ? BT0 : (z == 1 ? BT1 : BT2);
  int n0 = n_idx * 128, m0 = m_idx * 128;
  int t = threadIdx.x, lane = t & 63, w = t >> 6;
  int wy = w >> 1, wx = w & 1;
  int n16 = lane & 15, quad = lane >> 4;

  __shared__ __align__(16) unsigned short sA[3][128][32];
  __shared__ __align__(16) unsigned short sB[3][128][32];
  __shared__ __align__(16) unsigned short sDummy[512];  // tail sink (never read)
  const int BUFE = 128 * 32;

  int r4 = lane >> 2, c4 = lane & 3;
  const char* gA = (const char*)(A + (size_t)(m0 + w * 32 + r4) * K) + ((c4 ^ (r4 & 3)) * 16);
  const char* gB = (const char*)(BT + (size_t)(n0 + w * 32 + r4) * K) + ((c4 ^ (r4 & 3)) * 16);
  const size_t row16 = (size_t)16 * K * 2;
  unsigned short* stA = &sA[0][w * 32][0];
  unsigned short* stB = &sB[0][w * 32][0];

  int cs = (quad ^ (n16 & 3)) * 8;
  const unsigned short* rdA = &sA[0][wy * 64 + n16][0] + cs;
  const unsigned short* rdB = &sB[0][wx * 64 + n16][0] + cs;

  f32x4 acc[4][4];
#pragma unroll
  for (int i = 0; i < 4; ++i)
#pragma unroll
    for (int j = 0; j < 4; ++j) acc[i][j] = f32x4{0.f, 0.f, 0.f, 0.f};

  bf16x8 a[4], b[4];

#define QSTG(tt, dA, dB)                                                        \
  do {                                                                          \
    GLL16(gA + (size_t)(tt) * 64, (dA));                                        \
    GLL16(gA + (size_t)(tt) * 64 + row16, (dA) + 16 * 32);                      \
    GLL16(gB + (size_t)(tt) * 64, (dB));                                        \
    GLL16(gB + (size_t)(tt) * 64 + row16, (dB) + 16 * 32);                      \
  } while (0)

#define QRD(bufi)                                                               \
  do {                                                                          \
    _Pragma("unroll") for (int i = 0; i < 4; ++i) {                             \
      a[i] = *(const bf16x8*)(rdA + (bufi) * BUFE + (i * 16) * 32);             \
      b[i] = *(const bf16x8*)(rdB + (bufi) * BUFE + (i * 16) * 32);             \
    }                                                                           \
  } while (0)

#define QMM                                                                     \
  do {                                                                          \
    _Pragma("unroll") for (int mt = 0; mt < 4; ++mt)                            \
      _Pragma("unroll") for (int nt = 0; nt < 4; ++nt)                          \
        acc[mt][nt] = __builtin_amdgcn_mfma_f32_16x16x32_bf16(                  \
            a[mt], b[nt], acc[mt][nt], 0, 0, 0);                                \
  } while (0)

  // prologue: stage tiles 0,1 (8 loads); vmcnt(4) -> tile0 landed, tile1 in flight
  QSTG(0, stA, stB);
  QSTG(1, stA + BUFE, stB + BUFE);
  asm volatile("s_waitcnt vmcnt(4)" ::: "memory");
  __builtin_amdgcn_s_barrier();

#pragma unroll 3
  for (int kt = 0; kt < 30; ++kt) {
    int buf = kt % 3;
    int pfb = (kt + 2) % 3;
    QRD(buf);
    QSTG(kt + 2, stA + pfb * BUFE, stB + pfb * BUFE);
    QMM;
    asm volatile("s_waitcnt vmcnt(4)" ::: "memory");
    __builtin_amdgcn_s_barrier();
  }
  // tail: tiles 30 (buf 0) and 31 (buf 1); dummy staging keeps vmcnt uniform
  {
    QRD(0);
    QSTG(31, sDummy, sDummy);  // addresses valid (tile31 global), dest is sink
    QMM;
    asm volatile("s_waitcnt vmcnt(4)" ::: "memory");
    __builtin_amdgcn_s_barrier();
  }
  {
    QRD(1);
    QSTG(31, sDummy, sDummy);
    QMM;
    asm volatile("s_waitcnt vmcnt(0)" ::: "memory");  // drain sinks before epilogue
  }
#undef QSTG
#undef QRD
#undef QMM

  if (z < 2) {  // fused RoPE on Q/K; Q additionally pre-scaled by SCALE*log2(e)
    const float qs = (z == 0) ? (0.125f * 1.44269504088896340736f) : 1.0f;
#pragma unroll
    for (int mt = 0; mt < 4; ++mt)
#pragma unroll
      for (int r = 0; r < 4; ++r) {
        int row = m0 + wy * 64 + mt * 16 + quad * 4 + r;
        int b_ = row >> 11, s_ = row & 2047;
        int pos = pos_ids[b_ * 2048 + s_];
        const float* cb = cosb + (size_t)pos * 64;
        const float* sb = sinb + (size_t)pos * 64;
#pragma unroll
        for (int nt = 0; nt < 2; ++nt) {
          int d0 = nt * 16 + n16;
          float c0 = cb[d0] * qs, s0 = sb[d0] * qs;
          float c1 = cb[d0 + 32] * qs, s1 = sb[d0 + 32] * qs;
          float x0 = acc[mt][nt][r], x1 = acc[mt][nt + 2][r];
          acc[mt][nt][r]     = x0 * c0 - x1 * s0;
          acc[mt][nt + 2][r] = x1 * c1 + x0 * s1;
        }
      }
    unsigned short* dst = (z == 0) ? outQ : outK;
#pragma unroll
    for (int mt = 0; mt < 4; ++mt)
#pragma unroll
      for (int nt = 0; nt < 4; ++nt)
#pragma unroll
        for (int r = 0; r < 4; ++r) {
          int row = m0 + wy * 64 + mt * 16 + quad * 4 + r;
          int col = n0 + wx * 64 + nt * 16 + n16;
          int b_ = row >> 11, s_ = row & 2047, h_ = col >> 6, d_ = col & 63;
          dst[(((size_t)b_ * 16 + h_) * 2048 + s_) * 64 + d_] = f2bf(acc[mt][nt][r]);
        }
    return;
  }

  // z == 2: V^T fused write: VT[((b*16+h)*64+d)*2048 + s]; 4 consecutive s per lane
#pragma unroll
  for (int mt = 0; mt < 4; ++mt)
#pragma unroll
    for (int nt = 0; nt < 4; ++nt) {
      int row = m0 + wy * 64 + mt * 16 + quad * 4;  // +r stays within one b
      int b_ = row >> 11, s_ = row & 2047;
      int col = n0 + wx * 64 + nt * 16 + n16;
      int h_ = col >> 6, d_ = col & 63;
      ushortx4 u;
#pragma unroll
      for (int r = 0; r < 4; ++r) u[r] = f2bf(acc[mt][nt][r]);
      *(ushortx4*)(&outVT[(((size_t)b_ * 16 + h_) * 64 + d_) * 2048 + s_]) = u;
    }
}

// ---------------- Wo GEMM: 128x64 tile, BK=32, 3-deep ring, counted vmcnt ----
// M=4096 x N=1024 -> 512 blocks (2/CU). id = bx + 8*by, m fastest -> xcd = m%8
// (A-panels L2-pinned per XCD). 3 loads/thread/tile (2A+1B) -> trailing vmcnt(3).
__global__ __launch_bounds__(256) void wor_kernel(const unsigned short* __restrict__ A,
                                                  const unsigned short* __restrict__ BT,
                                                  float* __restrict__ outF) {
  const int K = 1024, N = 1024;
  int id = blockIdx.x + 8 * blockIdx.y;  // grid (8,64)
  int m_idx = id & 31, n_idx = id >> 5;
  int m0 = m_idx * 128, n0 = n_idx * 64;
  int t = threadIdx.x, lane = t & 63, w = t >> 6;
  int wy = w >> 1, wx = w & 1;
  int n16 = lane & 15, quad = lane >> 4;

  __shared__ __align__(16) unsigned short sA[3][128][32];
  __shared__ __align__(16) unsigned short sB[3][64][32];
  __shared__ __align__(16) unsigned short sDummy[512];
  const int BUFA = 128 * 32, BUFB = 64 * 32;

  int r4 = lane >> 2, c4 = lane & 3;
  const char* gA = (const char*)(A + (size_t)(m0 + w * 32 + r4) * K) + ((c4 ^ (r4 & 3)) * 16);
  const char* gB = (const char*)(BT + (size_t)(n0 + w * 16 + r4) * K) + ((c4 ^ (r4 & 3)) * 16);
  const size_t row16 = (size_t)16 * K * 2;
  unsigned short* stA = &sA[0][w * 32][0];
  unsigned short* stB = &sB[0][w * 16][0];

  int cs = (quad ^ (n16 & 3)) * 8;
  const unsigned short* rdA = &sA[0][wy * 64 + n16][0] + cs;
  const unsigned short* rdB = &sB[0][wx * 32 + n16][0] + cs;

  f32x4 acc[4][2];
#pragma unroll
  for (int i = 0; i < 4; ++i)
#pragma unroll
    for (int j = 0; j < 2; ++j) acc[i][j] = f32x4{0.f, 0.f, 0.f, 0.f};

  bf16x8 a[4], b[2];

#define WSTG(tt, dA, dB)                                                        \
  do {                                                                          \
    GLL16(gA + (size_t)(tt) * 64, (dA));                                        \
    GLL16(gA + (size_t)(tt) * 64 + row16, (dA) + 16 * 32);                      \
    GLL16(gB + (size_t)(tt) * 64, (dB));                                        \
  } while (0)

#define WRD(bufi)                                                               \
  do {                                                                          \
    _Pragma("unroll") for (int i = 0; i < 4; ++i)                               \
      a[i] = *(const bf16x8*)(rdA + (bufi) * BUFA + (i * 16) * 32);             \
    _Pragma("unroll") for (int j = 0; j < 2; ++j)                               \
      b[j] = *(const bf16x8*)(rdB + (bufi) * BUFB + (j * 16) * 32);             \
  } while (0)

#define WMM                                                                     \
  do {                                                                          \
    _Pragma("unroll") for (int mt = 0; mt < 4; ++mt)                            \
      _Pragma("unroll") for (int nt = 0; nt < 2; ++nt)                          \
        acc[mt][nt] = __builtin_amdgcn_mfma_f32_16x16x32_bf16(                  \
            a[mt], b[nt], acc[mt][nt], 0, 0, 0);                                \
  } while (0)

  WSTG(0, stA, stB);
  WSTG(1, stA + BUFA, stB + BUFB);
  asm volatile("s_waitcnt vmcnt(3)" ::: "memory");
  __builtin_amdgcn_s_barrier();

#pragma unroll 3
  for (int kt = 0; kt < 30; ++kt) {
    int buf = kt % 3;
    int pfb = (kt + 2) % 3;
    WRD(buf);
    WSTG(kt + 2, stA + pfb * BUFA, stB + pfb * BUFB);
    WMM;
    asm volatile("s_waitcnt vmcnt(3)" ::: "memory");
    __builtin_amdgcn_s_barrier();
  }
  {
    WRD(0);
    WSTG(31, sDummy, sDummy);
    WMM;
    asm volatile("s_waitcnt vmcnt(3)" ::: "memory");
    __builtin_amdgcn_s_barrier();
  }
  {
    WRD(1);
    WSTG(31, sDummy, sDummy);
    WMM;
    asm volatile("s_waitcnt vmcnt(0)" ::: "memory");
  }
#undef WSTG
#undef WRD
#undef WMM

#pragma unroll
  for (int mt = 0; mt < 4; ++mt)
#pragma unroll
    for (int nt = 0; nt < 2; ++nt)
#pragma unroll
      for (int r = 0; r < 4; ++r) {
        int row = m0 + wy * 64 + mt * 16 + quad * 4 + r;
        int col = n0 + wx * 32 + nt * 16 + n16;
        outF[(size_t)row * N + col] = acc[mt][nt][r];
      }
}

// ---------------- Flash attention: 4 waves, NO split-k, 40KB LDS (R9 base) ----
// R12 deltas vs R9 (VALU-count reduction only; schedule/layout untouched):
// (1) softmax in-place on sc (no p[][] copy);
// (2) P-pack + O-epilogue via native __bf16 casts (compiler emits v_cvt_pk_bf16_f32,
//     1 inst / 2 values, vs ~3 inst/value manual bit-math; RNE matches reference);
// (3) max-reduce as fmaxf triples (clang fuses to v_max3_f32, T17).
__global__ __launch_bounds__(256) void attn_kernel(const unsigned short* __restrict__ Q,
                                                   const unsigned short* __restrict__ Kk,
                                                   const unsigned short* __restrict__ VT,
                                                   unsigned short* __restrict__ O) {
  int bh = blockIdx.x;
  int qt = (int)(gridDim.y - 1 - blockIdx.y);  // LPT
  int t = threadIdx.x;
  int lane = t & 63;
  int w = t >> 6;          // 0..3
  int n16 = lane & 15, quad = lane >> 4;
  int r8 = lane >> 3, c8 = lane & 7;
  const unsigned short* Qb = Q + (size_t)bh * 2048 * 64;
  const unsigned short* Kb = Kk + (size_t)bh * 2048 * 64;
  const unsigned short* Vb = VT + (size_t)bh * 64 * 2048;

  __shared__ __align__(16) unsigned short sKV[2 * 8192];  // [buf][K 4096 | V 4096]
  __shared__ __align__(16) unsigned short sP[4][16 * 64];
  unsigned short* spW = sP[w];

  int b_ = bh >> 4, h_ = bh & 15;
  int nk = qt + 1;
  int qg = qt * 64 + w * 16 + n16;  // this lane's q-row

  bf16x8 aQ[2];
#pragma unroll
  for (int kb = 0; kb < 2; ++kb)
    aQ[kb] = *(const bf16x8*)(Qb + (size_t)qg * 64 + kb * 32 + quad * 8);

  f32x4 o[4];
  float mst = -3e38f, lst = 0.f;
#pragma unroll
  for (int ct = 0; ct < 4; ++ct) o[ct] = f32x4{0.f, 0.f, 0.f, 0.f};

#define ASTAGE(kt_, BUF)                                                                  \
  do {                                                                                    \
    const unsigned short* kg_ = Kb + (size_t)((kt_) * 64 + w * 16) * 64;                  \
    const unsigned short* vg_ = Vb + (size_t)(w * 16) * 2048 + (kt_) * 64;                \
    unsigned short* dK = sKV + (BUF) * 8192 + (w * 16) * 64;                              \
    unsigned short* dV = dK + 4096;                                                       \
    GLL16(kg_ + (size_t)r8 * 64 + (c8 ^ r8) * 8, dK);                                     \
    GLL16(kg_ + (size_t)(8 + r8) * 64 + (c8 ^ r8) * 8, dK + 8 * 64);                      \
    GLL16(vg_ + (size_t)r8 * 2048 + (c8 ^ r8) * 8, dV);                                   \
    GLL16(vg_ + (size_t)(8 + r8) * 2048 + (c8 ^ r8) * 8, dV + 8 * 64);                    \
  } while (0)

#define ACOMPUTE(kt_, BUF)                                                                \
  do {                                                                                    \
    const unsigned short* kT_ = sKV + (BUF) * 8192;                                       \
    const unsigned short* vT_ = kT_ + 4096;                                               \
    f32x4 sc[4]; /* S^T: D[m=k][n=q], A=K-frag, B=Q-frag */                               \
    _Pragma("unroll") for (int mt = 0; mt < 4; ++mt) {                                    \
      const unsigned short* kr = &kT_[(mt * 16 + n16) * 64];                              \
      bf16x8 ka0 = *(const bf16x8*)(kr + ((quad ^ (n16 & 7)) * 8));                       \
      bf16x8 ka1 = *(const bf16x8*)(kr + (((4 + quad) ^ (n16 & 7)) * 8));                 \
      f32x4 zv = f32x4{0.f, 0.f, 0.f, 0.f};                                               \
      zv = __builtin_amdgcn_mfma_f32_16x16x32_bf16(ka0, aQ[0], zv, 0, 0, 0);              \
      sc[mt] = __builtin_amdgcn_mfma_f32_16x16x32_bf16(ka1, aQ[1], zv, 0, 0, 0);          \
    }                                                                                     \
    if ((kt_) == nk - 1) { /* diagonal tile: mask k > q */                                \
      int kb0 = (kt_) * 64 + quad * 4;                                                    \
      _Pragma("unroll") for (int mt = 0; mt < 4; ++mt)                                    \
        _Pragma("unroll") for (int r = 0; r < 4; ++r)                                     \
          if (kb0 + mt * 16 + r > qg) sc[mt][r] = -3e38f;                                 \
    }                                                                                     \
    /* max3-friendly tree reduce over the 16 values */                                    \
    float g0 = fmaxf(fmaxf(sc[0][0], sc[0][1]), sc[0][2]);                                \
    float g1 = fmaxf(fmaxf(sc[0][3], sc[1][0]), sc[1][1]);                                \
    float g2 = fmaxf(fmaxf(sc[1][2], sc[1][3]), sc[2][0]);                                \
    float g3 = fmaxf(fmaxf(sc[2][1], sc[2][2]), sc[2][3]);                                \
    float g4 = fmaxf(fmaxf(sc[3][0], sc[3][1]), sc[3][2]);                                \
    float rm = fmaxf(fmaxf(fmaxf(g0, g1), fmaxf(g2, g3)),                                 \
                     fmaxf(g4, sc[3][3]));                                                \
    rm = fmaxf(rm, __shfl_xor(rm, 16));                                                   \
    rm = fmaxf(rm, __shfl_xor(rm, 32));                                                   \
    if (!__all(rm <= mst + 8.f)) { /* T13 defer-max: rescale only on real growth */       \
      float mn = fmaxf(mst, rm);                                                          \
      float al = exp2f(mst - mn);                                                         \
      mst = mn;                                                                           \
      lst *= al;                                                                          \
      _Pragma("unroll") for (int ct = 0; ct < 4; ++ct)                                    \
        _Pragma("unroll") for (int r = 0; r < 4; ++r) o[ct][r] *= al;                     \
    }                                                                                     \
    float rs = 0.f;                                                                       \
    _Pragma("unroll") for (int mt = 0; mt < 4; ++mt)                                      \
      _Pragma("unroll") for (int r = 0; r < 4; ++r) {                                     \
        sc[mt][r] = exp2f(sc[mt][r] - mst);                                               \
        rs += sc[mt][r];                                                                  \
      }                                                                                   \
    lst += rs;                                                                            \
    _Pragma("unroll") for (int mt = 0; mt < 4; ++mt) {                                    \
      bf16x4 uu;                                                                          \
      _Pragma("unroll") for (int r = 0; r < 4; ++r) uu[r] = (__bf16)sc[mt][r];            \
      int ch = (mt * 2 + (quad >> 1)) ^ (n16 & 7);                                        \
      *(bf16x4*)(&spW[n16 * 64 + ch * 8 + (quad & 1) * 4]) = uu;                          \
    }                                                                                     \
    __builtin_amdgcn_s_waitcnt(0xC07F); /* lgkmcnt(0); GLL prefetch stays in flight */    \
    bf16x8 aP0 = *(const bf16x8*)(&spW[n16 * 64 + ((quad ^ (n16 & 7)) * 8)]);             \
    bf16x8 aP1 = *(const bf16x8*)(&spW[n16 * 64 + (((4 + quad) ^ (n16 & 7)) * 8)]);       \
    _Pragma("unroll") for (int ct = 0; ct < 4; ++ct) {                                    \
      const unsigned short* vr = &vT_[(ct * 16 + n16) * 64];                              \
      bf16x8 va0 = *(const bf16x8*)(vr + ((quad ^ (n16 & 7)) * 8));                       \
      bf16x8 va1 = *(const bf16x8*)(vr + (((4 + quad) ^ (n16 & 7)) * 8));                 \
      o[ct] = __builtin_amdgcn_mfma_f32_16x16x32_bf16(va0, aP0, o[ct], 0, 0, 0);          \
      o[ct] = __builtin_amdgcn_mfma_f32_16x16x32_bf16(va1, aP1, o[ct], 0, 0, 0);          \
    }                                                                                     \
  } while (0)

  ASTAGE(0, 0);
  int it = 0;
  while (it < nk) {
    __syncthreads();  // drains loads into buf0 (nk is block-uniform)
    {
      int kt = it;
      if (kt + 1 < nk) ASTAGE(kt + 1, 1);
      ACOMPUTE(kt, 0);
    }
    if (++it >= nk) break;
    __syncthreads();  // drains loads into buf1
    {
      int kt = it;
      if (kt + 1 < nk) ASTAGE(kt + 1, 0);
      ACOMPUTE(kt, 1);
    }
    ++it;
  }
#undef ASTAGE
#undef ACOMPUTE

  // finish lane-partial l (cross-quad k-partials) and write output
  lst += __shfl_xor(lst, 16);
  lst += __shfl_xor(lst, 32);
  float inv = 1.0f / lst;
#pragma unroll
  for (int ct = 0; ct < 4; ++ct) {
    bf16x4 uo;
#pragma unroll
    for (int r = 0; r < 4; ++r) uo[r] = (__bf16)(o[ct][r] * inv);
    size_t addr = ((size_t)b_ * 2048 + qg) * 1024 + h_ * 64 + ct * 16 + quad * 4;
    *(bf16x4*)(&O[addr]) = uo;
  }
}

// ---------------- launch ----------------
extern "C" void kernel_launch(void* const* d_in, const int* in_sizes, int n_in,
                              void* d_out, int out_size, void* d_ws, size_t ws_size,
                              hipStream_t stream) {
  const float* X    = (const float*)d_in[0];
  const int*   pos  = (const int*)d_in[2];
  const float* cosb = (const float*)d_in[3];
  const float* sinb = (const float*)d_in[4];
  const float* Wq   = (const float*)d_in[5];
  const float* Wk   = (const float*)d_in[6];
  const float* Wv   = (const float*)d_in[7];
  const float* Wo   = (const float*)d_in[8];
  float* out = (float*)d_out;

  char* ws = (char*)d_ws;
  const size_t SZ_X = 4096UL * 1024 * 2;
  const size_t SZ_W = 1024UL * 1024 * 2;
  unsigned short* Xbf = (unsigned short*)(ws);
  unsigned short* WTq = (unsigned short*)(ws + SZ_X);
  unsigned short* WTk = (unsigned short*)(ws + SZ_X + SZ_W);
  unsigned short* WTv = (unsigned short*)(ws + SZ_X + 2 * SZ_W);
  unsigned short* WTo = (unsigned short*)(ws + SZ_X + 3 * SZ_W);
  unsigned short* Qbf = (unsigned short*)(ws + SZ_X + 4 * SZ_W);
  unsigned short* Kbf = (unsigned short*)(ws + 2 * SZ_X + 4 * SZ_W);
  unsigned short* VTr = (unsigned short*)(ws + 3 * SZ_X + 4 * SZ_W);
  unsigned short* Obf = (unsigned short*)(ws + 4 * SZ_X + 4 * SZ_W);

  prep_kernel<<<dim3(32, 32, 6), dim3(32, 8), 0, stream>>>(
      X, Wq, Wk, Wv, Wo, Xbf, WTq, WTk, WTv, WTo);

  // QKV projections + fused RoPE (Q pre-scaled) + fused V-transpose, 128^2 ring
  qkvr_kernel<<<dim3(8, 32, 3), 256, 0, stream>>>(Xbf, WTq, WTk, WTv,
                                                  Qbf, Kbf, VTr,
                                                  pos, cosb, sinb);

  // attention: 4-wave blocks, 40KB LDS, reduced-VALU softmax
  attn_kernel<<<dim3(32, 32), 256, 0, stream>>>(Qbf, Kbf, VTr, Obf);

  // Wo GEMM: 128x64 ring, 512 blocks
  wor_kernel<<<dim3(8, 64), 256, 0, stream>>>(Obf, WTo, out);
}